// Round 17
// baseline (115.385 us; speedup 1.0000x reference)
//
#include <hip/hip_runtime.h>
#include <math.h>

#define NT 64
#define L_LEN 720
#define NROWS (64 * 321)   // 20544

#define LOG2E 1.4426950408889634f
#define LN2   0.6931471805599453f

typedef float f32x2 __attribute__((ext_vector_type(2)));

__device__ __forceinline__ f32x2 pkfma(f32x2 a, f32x2 b, f32x2 c) {
    return __builtin_elementwise_fma(a, b, c);   // -> v_pk_fma_f32
}

// uniform float -> SGPR (frees a VGPR; pk ops may read 1 scalar operand)
__device__ __forceinline__ float rfl(float v) {
    return __int_as_float(__builtin_amdgcn_readfirstlane(__float_as_int(v)));
}

// ---- DPP wave reductions: pure VALU pipe, no LDS, no lgkmcnt stalls ----
template<int CTRL, int RM>
__device__ __forceinline__ float dpp_add(float x) {
    int t = __builtin_amdgcn_update_dpp(0, __float_as_int(x), CTRL, RM, 0xf, true);
    return x + __int_as_float(t);
}

__device__ __forceinline__ float wave_sum64(float x) {
    x = dpp_add<0x111, 0xf>(x);   // row_shr:1
    x = dpp_add<0x112, 0xf>(x);   // row_shr:2
    x = dpp_add<0x114, 0xf>(x);   // row_shr:4
    x = dpp_add<0x118, 0xf>(x);   // row_shr:8
    x = dpp_add<0x142, 0xa>(x);   // row_bcast:15 -> rows 1,3
    x = dpp_add<0x143, 0xc>(x);   // row_bcast:31 -> rows 2,3 ; lane63 = total
    return __int_as_float(__builtin_amdgcn_readlane(__float_as_int(x), 63));
}

__device__ __forceinline__ float half_sum32(float x) {
    x = dpp_add<0x111, 0xf>(x);
    x = dpp_add<0x112, 0xf>(x);
    x = dpp_add<0x114, 0xf>(x);
    x = dpp_add<0x118, 0xf>(x);
    x = dpp_add<0x142, 0xa>(x);   // lane31 = sum lanes 0..31
    return __int_as_float(__builtin_amdgcn_readlane(__float_as_int(x), 31));
}

__global__ __launch_bounds__(NT, 6) void trend_kernel(
    const float* __restrict__ x,
    const float* __restrict__ cw0, const float* __restrict__ cb0,
    const float* __restrict__ cw1, const float* __restrict__ cb1,
    const float* __restrict__ cw2, const float* __restrict__ cb2,
    const float* __restrict__ cw3, const float* __restrict__ cb3,
    const float* __restrict__ W1, const float* __restrict__ b1,
    const float* __restrict__ W2, const float* __restrict__ b2,
    float* __restrict__ out)
{
    // 1 wave/block; SMALL live set (pairs only, no kept conv outputs) so the
    // (64,6) VGPR cap (85) fits cleanly -> 6 waves/SIMD to hide the cold-read
    // head latency. Output recomputed as merged 9-tap conv (R14 style).
    const int lane = threadIdx.x;            // 0..63
    const int row  = blockIdx.x;

    const float* __restrict__ xr = x + (size_t)row * L_LEN;

    // ---- loads first (lanes 60..63 shadow lane 59; masked later)
    const int ll = (lane < 60) ? lane : 59;
    const int e0 = 12 * ll - 4;
    float xw[20];
#pragma unroll
    for (int q = 0; q < 5; ++q) {
        int e = e0 + 4 * q;
        e = (e < 0) ? 0 : ((e > L_LEN - 4) ? (L_LEN - 4) : e);   // 16B-aligned
        float4 v = *(const float4*)(xr + e);
        xw[4 * q + 0] = v.x; xw[4 * q + 1] = v.y;
        xw[4 * q + 2] = v.z; xw[4 * q + 3] = v.w;
    }

    // ---- uniform weights -> SGPRs under the load shadow (LOG2E pre-folded)
    const float* cws[4] = {cw0, cw1, cw2, cw3};
    const float* cbs[4] = {cb0, cb1, cb2, cb3};
    float w2[4][9], bs2[4];
#pragma unroll
    for (int s = 0; s < 4; ++s) {
        const int k = 3 + 2 * s;
        bs2[s] = rfl(cbs[s][0] * LOG2E);
#pragma unroll
        for (int t = 0; t < 9; ++t)
            w2[s][t] = (t < k) ? rfl(cws[s][t] * LOG2E) : 0.0f;
    }

    // row-edge zero padding
    if (lane == 0)  { xw[0] = 0.f; xw[1] = 0.f; xw[2] = 0.f; xw[3] = 0.f; }
    if (lane == 59) { xw[16] = 0.f; xw[17] = 0.f; xw[18] = 0.f; xw[19] = 0.f; }

    // ---- stride-6 pair view: p[i] = (xw[i], xw[i+6]); xw dies here.
    f32x2 p[14];
#pragma unroll
    for (int i = 0; i < 14; ++i) p[i] = (f32x2){xw[i], xw[i + 6]};
    // pin the pairs: loads happen exactly once, survive to the output pass
#pragma unroll
    for (int i = 0; i < 14; ++i) {
        asm volatile("" : "+v"(p[i].x));
        asm volatile("" : "+v"(p[i].y));
    }

    // ---- pass 1: conv(u) -> 2^u -> accumulate S, Tu (nothing kept)
    f32x2 Spk[4] = {{0.f,0.f},{0.f,0.f},{0.f,0.f},{0.f,0.f}};
    f32x2 Tpk[4] = {{0.f,0.f},{0.f,0.f},{0.f,0.f},{0.f,0.f}};
#pragma unroll
    for (int j = 0; j < 6; ++j) {
#pragma unroll
        for (int s = 0; s < 4; ++s) {
            const int k = 3 + 2 * s;
            const int off = 3 - s;              // 4 - k/2
            f32x2 u = (f32x2){bs2[s], bs2[s]};
#pragma unroll
            for (int t = 0; t < k; ++t) {
                const f32x2 wv = (f32x2){w2[s][t], w2[s][t]};
                u = pkfma(wv, p[j + off + t], u);
            }
            f32x2 ev;
            ev.x = __builtin_amdgcn_exp2f(u.x);
            ev.y = __builtin_amdgcn_exp2f(u.y);
            Spk[s] += ev;
            Tpk[s] = pkfma(u, ev, Tpk[s]);
        }
    }

    // combine packed halves; mask lanes 60..63 (duplicates of 59)
    const bool active = lane < 60;
    float S[4], Tu[4];
#pragma unroll
    for (int s = 0; s < 4; ++s) {
        S[s]  = active ? (Spk[s].x + Spk[s].y) : 0.0f;
        Tu[s] = active ? (Tpk[s].x + Tpk[s].y) : 0.0f;
    }

    // wave totals via DPP; entropy = ln2 * (log2 S - Tu/S), wave-uniform
    float ent[4];
#pragma unroll
    for (int s = 0; s < 4; ++s) {
        float Sg = wave_sum64(S[s]);
        float Tg = wave_sum64(Tu[s]);
        ent[s] = LN2 * (__builtin_amdgcn_logf(Sg)
                        - Tg * __builtin_amdgcn_rcpf(Sg));
    }

    // MLP: hidden unit per lane (mod 32); logits via DPP 32-lane sums
    const int hidx = lane & 31;
    float h = b1[hidx];
#pragma unroll
    for (int s = 0; s < 4; ++s) h = fmaf(ent[s], W1[s * 32 + hidx], h);
    h = fmaxf(h, 0.0f);

    const float4 w2v = ((const float4*)W2)[hidx];
    float lg0 = half_sum32(h * w2v.x) + b2[0];
    float lg1 = half_sum32(h * w2v.y) + b2[1];
    float lg2 = half_sum32(h * w2v.z) + b2[2];
    float lg3 = half_sum32(h * w2v.w) + b2[3];

    // softmax (wave-uniform); LN2 folded into the mixing weights
    float m = fmaxf(fmaxf(lg0, lg1), fmaxf(lg2, lg3));
    float e0w = __expf(lg0 - m), e1w = __expf(lg1 - m);
    float e2w = __expf(lg2 - m), e3w = __expf(lg3 - m);
    float inv = LN2 / (e0w + e1w + e2w + e3w);
    const float wg0 = e0w * inv, wg1 = e1w * inv;
    const float wg2 = e2w * inv, wg3 = e3w * inv;

    // merged 9-tap output kernel (wave-uniform, ~44 one-time issues)
    float Wm[9] = {0,0,0,0,0,0,0,0,0};
    float Bm = 0.f;
    {
        const float wgt[4] = {wg0, wg1, wg2, wg3};
#pragma unroll
        for (int s = 0; s < 4; ++s) {
            const int k = 3 + 2 * s;
            const int off = 3 - s;
#pragma unroll
            for (int t = 0; t < k; ++t)
                Wm[off + t] = rfl(fmaf(wgt[s], w2[s][t], Wm[off + t]));
            Bm = fmaf(wgt[s], bs2[s], Bm);
        }
        Bm = rfl(Bm);
    }

    // ---- pass 2: merged packed conv from the pinned pairs
    if (active) {
        f32x2 o[6];
#pragma unroll
        for (int j = 0; j < 6; ++j) {
            f32x2 acc = (f32x2){Bm, Bm};
#pragma unroll
            for (int d = 0; d < 9; ++d) {
                const f32x2 wv = (f32x2){Wm[d], Wm[d]};
                acc = pkfma(wv, p[j + d], acc);
            }
            o[j] = acc;
        }
        // elements: j -> o[j].x (0..5), j+6 -> o[j].y (6..11)
        float* __restrict__ orow = out + (size_t)row * L_LEN + 12 * lane;
        float4 v0 = {o[0].x, o[1].x, o[2].x, o[3].x};
        float4 v1 = {o[4].x, o[5].x, o[0].y, o[1].y};
        float4 v2 = {o[2].y, o[3].y, o[4].y, o[5].y};
        *(float4*)(orow)     = v0;
        *(float4*)(orow + 4) = v1;
        *(float4*)(orow + 8) = v2;
    }
}

extern "C" void kernel_launch(void* const* d_in, const int* in_sizes, int n_in,
                              void* d_out, int out_size, void* d_ws, size_t ws_size,
                              hipStream_t stream) {
    const float* xp  = (const float*)d_in[0];
    const float* cw0 = (const float*)d_in[1];
    const float* cb0 = (const float*)d_in[2];
    const float* cw1 = (const float*)d_in[3];
    const float* cb1 = (const float*)d_in[4];
    const float* cw2 = (const float*)d_in[5];
    const float* cb2 = (const float*)d_in[6];
    const float* cw3 = (const float*)d_in[7];
    const float* cb3 = (const float*)d_in[8];
    const float* W1  = (const float*)d_in[9];
    const float* b1  = (const float*)d_in[10];
    const float* W2  = (const float*)d_in[11];
    const float* b2  = (const float*)d_in[12];
    float* outp = (float*)d_out;

    trend_kernel<<<NROWS, NT, 0, stream>>>(xp, cw0, cb0, cw1, cb1, cw2, cb2,
                                           cw3, cb3, W1, b1, W2, b2, outp);
}

// Round 18
// 33.030 us; speedup vs baseline: 3.4933x; 3.4933x over previous
//
#include <hip/hip_runtime.h>
#include <math.h>

#define NT 64
#define L_LEN 720
#define NROWS (64 * 321)   // 20544

#define LOG2E 1.4426950408889634f
#define LN2   0.6931471805599453f

typedef float f32x2 __attribute__((ext_vector_type(2)));

__device__ __forceinline__ f32x2 pkfma(f32x2 a, f32x2 b, f32x2 c) {
    return __builtin_elementwise_fma(a, b, c);   // -> v_pk_fma_f32
}

// ---- DPP wave reductions: pure VALU pipe, no LDS, no lgkmcnt stalls ----
template<int CTRL, int RM>
__device__ __forceinline__ float dpp_add(float x) {
    int t = __builtin_amdgcn_update_dpp(0, __float_as_int(x), CTRL, RM, 0xf, true);
    return x + __int_as_float(t);
}

__device__ __forceinline__ float wave_sum64(float x) {
    x = dpp_add<0x111, 0xf>(x);   // row_shr:1
    x = dpp_add<0x112, 0xf>(x);   // row_shr:2
    x = dpp_add<0x114, 0xf>(x);   // row_shr:4
    x = dpp_add<0x118, 0xf>(x);   // row_shr:8
    x = dpp_add<0x142, 0xa>(x);   // row_bcast:15 -> rows 1,3
    x = dpp_add<0x143, 0xc>(x);   // row_bcast:31 -> rows 2,3 ; lane63 = total
    return __int_as_float(__builtin_amdgcn_readlane(__float_as_int(x), 63));
}

__device__ __forceinline__ float half_sum32(float x) {
    x = dpp_add<0x111, 0xf>(x);
    x = dpp_add<0x112, 0xf>(x);
    x = dpp_add<0x114, 0xf>(x);
    x = dpp_add<0x118, 0xf>(x);
    x = dpp_add<0x142, 0xa>(x);   // lane31 = sum lanes 0..31
    return __int_as_float(__builtin_amdgcn_readlane(__float_as_int(x), 31));
}

__global__ __launch_bounds__(NT, 4) void trend_kernel(
    const float* __restrict__ x,
    const float* __restrict__ cw0, const float* __restrict__ cb0,
    const float* __restrict__ cw1, const float* __restrict__ cb1,
    const float* __restrict__ cw2, const float* __restrict__ cb2,
    const float* __restrict__ cw3, const float* __restrict__ cb3,
    const float* __restrict__ W1, const float* __restrict__ b1,
    const float* __restrict__ W2, const float* __restrict__ b2,
    float* __restrict__ out)
{
    // R15 base (1 wave/block, packed fp32, DPP, fu kept in regs) with the
    // weight-setup VALU deleted: RAW weights via uniform scalar loads
    // (SALU, zero VALU cost), conv in natural units, LOG2E applied as a
    // packed mul only where exp2 needs it. MLP operand loads hoisted early.
    const int lane = threadIdx.x;            // 0..63
    const int row  = blockIdx.x;

    const float* __restrict__ xr = x + (size_t)row * L_LEN;

    // ---- x loads first (lanes 60..63 shadow lane 59; masked later)
    const int ll = (lane < 60) ? lane : 59;
    const int e0 = 12 * ll - 4;
    float xw[20];
#pragma unroll
    for (int q = 0; q < 5; ++q) {
        int e = e0 + 4 * q;
        e = (e < 0) ? 0 : ((e > L_LEN - 4) ? (L_LEN - 4) : e);   // 16B-aligned
        float4 v = *(const float4*)(xr + e);
        xw[4 * q + 0] = v.x; xw[4 * q + 1] = v.y;
        xw[4 * q + 2] = v.z; xw[4 * q + 3] = v.w;
    }

    // ---- MLP operand loads issued early (hide under conv)
    const int hidx = lane & 31;
    float w1r[4];
#pragma unroll
    for (int s = 0; s < 4; ++s) w1r[s] = W1[s * 32 + hidx];
    const float b1r = b1[hidx];
    const float4 w2v = ((const float4*)W2)[hidx];
    const float b20 = b2[0], b21 = b2[1], b22 = b2[2], b23 = b2[3];

    // ---- RAW weights: uniform addresses -> scalar (SALU) loads, no VALU
    const float* cws[4] = {cw0, cw1, cw2, cw3};
    const float* cbs[4] = {cb0, cb1, cb2, cb3};
    float w[4][9], bs[4];
#pragma unroll
    for (int s = 0; s < 4; ++s) {
        const int k = 3 + 2 * s;
        bs[s] = cbs[s][0];
#pragma unroll
        for (int t = 0; t < 9; ++t)
            w[s][t] = (t < k) ? cws[s][t] : 0.0f;
    }

    // row-edge zero padding
    if (lane == 0)  { xw[0] = 0.f; xw[1] = 0.f; xw[2] = 0.f; xw[3] = 0.f; }
    if (lane == 59) { xw[16] = 0.f; xw[17] = 0.f; xw[18] = 0.f; xw[19] = 0.f; }

    // pin window (loads happen exactly once)
#pragma unroll
    for (int t = 0; t < 20; ++t) asm volatile("" : "+v"(xw[t]));

    // ---- stride-6 pair view: p[i] = (xw[i], xw[i+6]), i = 0..13
    f32x2 p[14];
#pragma unroll
    for (int i = 0; i < 14; ++i) p[i] = (f32x2){xw[i], xw[i + 6]};

    // ---- fused pass: conv f (natural) kept in regs -> u = f*log2e (packed)
    //      -> 2^u -> accumulate S (=sum e^f), Tn (=sum f e^f)
    const f32x2 l2e = (f32x2){LOG2E, LOG2E};
    f32x2 fu[4][6];
    f32x2 Spk[4] = {{0.f,0.f},{0.f,0.f},{0.f,0.f},{0.f,0.f}};
    f32x2 Tpk[4] = {{0.f,0.f},{0.f,0.f},{0.f,0.f},{0.f,0.f}};
#pragma unroll
    for (int j = 0; j < 6; ++j) {
#pragma unroll
        for (int s = 0; s < 4; ++s) {
            const int k = 3 + 2 * s;
            const int off = 3 - s;              // 4 - k/2
            f32x2 f = (f32x2){bs[s], bs[s]};
#pragma unroll
            for (int t = 0; t < k; ++t) {
                const f32x2 wv = (f32x2){w[s][t], w[s][t]};
                f = pkfma(wv, p[j + off + t], f);
            }
            fu[s][j] = f;
            f32x2 u = f * l2e;                  // one v_pk_mul
            f32x2 ev;
            ev.x = __builtin_amdgcn_exp2f(u.x);
            ev.y = __builtin_amdgcn_exp2f(u.y);
            Spk[s] += ev;
            Tpk[s] = pkfma(f, ev, Tpk[s]);      // natural units
        }
    }

    // pin fu: conv computed exactly once (no remat through the tail)
#pragma unroll
    for (int s = 0; s < 4; ++s)
#pragma unroll
        for (int j = 0; j < 6; ++j) {
            asm volatile("" : "+v"(fu[s][j].x));
            asm volatile("" : "+v"(fu[s][j].y));
        }

    // combine packed halves; mask lanes 60..63 (duplicates of 59)
    const bool active = lane < 60;
    float S[4], Tn[4];
#pragma unroll
    for (int s = 0; s < 4; ++s) {
        S[s]  = active ? (Spk[s].x + Spk[s].y) : 0.0f;
        Tn[s] = active ? (Tpk[s].x + Tpk[s].y) : 0.0f;
    }

    // wave totals via DPP; entropy = ln S - T/S = ln2*log2(S) - Tn/S
    float ent[4];
#pragma unroll
    for (int s = 0; s < 4; ++s) {
        float Sg = wave_sum64(S[s]);
        float Tg = wave_sum64(Tn[s]);
        ent[s] = fmaf(LN2, __builtin_amdgcn_logf(Sg),
                      -Tg * __builtin_amdgcn_rcpf(Sg));
    }

    // MLP: hidden unit per lane (mod 32); logits via DPP 32-lane sums
    float h = b1r;
#pragma unroll
    for (int s = 0; s < 4; ++s) h = fmaf(ent[s], w1r[s], h);
    h = fmaxf(h, 0.0f);

    float lg0 = half_sum32(h * w2v.x) + b20;
    float lg1 = half_sum32(h * w2v.y) + b21;
    float lg2 = half_sum32(h * w2v.z) + b22;
    float lg3 = half_sum32(h * w2v.w) + b23;

    // softmax (wave-uniform); weights apply to natural f directly
    float m = fmaxf(fmaxf(lg0, lg1), fmaxf(lg2, lg3));
    float e0w = __expf(lg0 - m), e1w = __expf(lg1 - m);
    float e2w = __expf(lg2 - m), e3w = __expf(lg3 - m);
    float inv = 1.0f / (e0w + e1w + e2w + e3w);
    const float wg0 = e0w * inv, wg1 = e1w * inv;
    const float wg2 = e2w * inv, wg3 = e3w * inv;

    // ---- output directly from the kept natural-unit f pairs: 4 pkfma/pair
    if (active) {
        f32x2 o[6];
#pragma unroll
        for (int j = 0; j < 6; ++j) {
            f32x2 acc = (f32x2){wg0, wg0} * fu[0][j];
            acc = pkfma((f32x2){wg1, wg1}, fu[1][j], acc);
            acc = pkfma((f32x2){wg2, wg2}, fu[2][j], acc);
            acc = pkfma((f32x2){wg3, wg3}, fu[3][j], acc);
            o[j] = acc;
        }
        // elements: j -> o[j].x (0..5), j+6 -> o[j].y (6..11); repack to float4
        float* __restrict__ orow = out + (size_t)row * L_LEN + 12 * lane;
        float4 v0 = {o[0].x, o[1].x, o[2].x, o[3].x};
        float4 v1 = {o[4].x, o[5].x, o[0].y, o[1].y};
        float4 v2 = {o[2].y, o[3].y, o[4].y, o[5].y};
        *(float4*)(orow)     = v0;
        *(float4*)(orow + 4) = v1;
        *(float4*)(orow + 8) = v2;
    }
}

extern "C" void kernel_launch(void* const* d_in, const int* in_sizes, int n_in,
                              void* d_out, int out_size, void* d_ws, size_t ws_size,
                              hipStream_t stream) {
    const float* xp  = (const float*)d_in[0];
    const float* cw0 = (const float*)d_in[1];
    const float* cb0 = (const float*)d_in[2];
    const float* cw1 = (const float*)d_in[3];
    const float* cb1 = (const float*)d_in[4];
    const float* cw2 = (const float*)d_in[5];
    const float* cb2 = (const float*)d_in[6];
    const float* cw3 = (const float*)d_in[7];
    const float* cb3 = (const float*)d_in[8];
    const float* W1  = (const float*)d_in[9];
    const float* b1  = (const float*)d_in[10];
    const float* W2  = (const float*)d_in[11];
    const float* b2  = (const float*)d_in[12];
    float* outp = (float*)d_out;

    trend_kernel<<<NROWS, NT, 0, stream>>>(xp, cw0, cb0, cw1, cb1, cw2, cb2,
                                           cw3, cb3, W1, b1, W2, b2, outp);
}